// Round 14
// baseline (87.418 us; speedup 1.0000x reference)
//
#include <hip/hip_runtime.h>
#include <hip/hip_bf16.h>
#include <math.h>

#define NTOK 10000
#define BATCH 2
#define CDIM 128
#define NHEAD 4
#define NPNT 20
#define DHEAD 32
#define HWDIM 100
#define MROWS (BATCH * NTOK)
#define OPAD 384   // 128 value rows + 4 heads x (40 off + 20 attn + 4 pad)
#define PTOK 8
#define PHALO 4
#define PDIM 16
#define NPATCH 13
#define CELLPAD 40 // bf16 per cell in LDS (stride 80B: 16B-aligned)

typedef __attribute__((ext_vector_type(8))) short short8v;
typedef __attribute__((ext_vector_type(4))) short short4v;
typedef __attribute__((ext_vector_type(4))) float f32x4;

__device__ __forceinline__ float asf(unsigned u) {
  union { unsigned u; float f; } c; c.u = u; return c.f;
}

// unpack 8 bf16 (16B) and accumulate w * g into two f32x4 accumulators
__device__ __forceinline__ void acc_cell(const __hip_bfloat16* p, float w,
                                         f32x4& a0, f32x4& a1) {
  int4 u = *(const int4*)p;
  f32x4 g0, g1;
  g0.x = asf(((unsigned)u.x) << 16); g0.y = asf(((unsigned)u.x) & 0xFFFF0000u);
  g0.z = asf(((unsigned)u.y) << 16); g0.w = asf(((unsigned)u.y) & 0xFFFF0000u);
  g1.x = asf(((unsigned)u.z) << 16); g1.y = asf(((unsigned)u.z) & 0xFFFF0000u);
  g1.z = asf(((unsigned)u.w) << 16); g1.w = asf(((unsigned)u.w) & 0xFFFF0000u);
  a0 += g0 * w;
  a1 += g1 * w;
}

// ---------------------------------------------------------------------------
// prep: blocks [0,384): Wcat row blk (bf16) + bcat[blk].
//   row < 128: W_val row. row in [128,384): h=(row-128)>>6, k=(row-128)&63:
//   k<40 -> W_off[h*40+k]; 40<=k<60 -> W_attn[h*20+k-40]; else zero pad.
// blocks [384,512): fold Wc = W2@W1 row -> Wc_bf, bc (for proj2).
// ---------------------------------------------------------------------------
__global__ __launch_bounds__(128) void prep_kernel(
    const float* __restrict__ W_val, const float* __restrict__ b_val,
    const float* __restrict__ W_off, const float* __restrict__ b_off,
    const float* __restrict__ W_attn, const float* __restrict__ b_attn,
    const float* __restrict__ W1, const float* __restrict__ b1,
    const float* __restrict__ W2, const float* __restrict__ b2,
    __hip_bfloat16* __restrict__ Wcat, float* __restrict__ bcat,
    __hip_bfloat16* __restrict__ Wc_bf, float* __restrict__ bc) {
  __shared__ float w2row[128];
  __shared__ float red[128];
  const int blk = blockIdx.x, c = threadIdx.x;
  if (blk < OPAD) {
    float v = 0.f, bv = 0.f;
    if (blk < 128) {
      v = W_val[blk * 128 + c]; bv = b_val[blk];
    } else {
      int h = (blk - 128) >> 6, k = (blk - 128) & 63;
      if (k < 40) { v = W_off[(h * 40 + k) * 128 + c]; bv = b_off[h * 40 + k]; }
      else if (k < 60) { v = W_attn[(h * 20 + k - 40) * 128 + c]; bv = b_attn[h * 20 + k - 40]; }
    }
    Wcat[(size_t)blk * 128 + c] = __float2bfloat16(v);
    if (c == 0) bcat[blk] = bv;
  } else {
    const int o = blk - OPAD;  // 0..127
    w2row[c] = W2[o * 128 + c];
    __syncthreads();
    float acc = 0.f;
    for (int k = 0; k < 128; ++k) acc += w2row[k] * W1[k * 128 + c];
    Wc_bf[(size_t)o * 128 + c] = __float2bfloat16(acc);
    red[c] = w2row[c] * b1[c];
    __syncthreads();
    for (int s = 64; s > 0; s >>= 1) {
      if (c < s) red[c] += red[c + s];
      __syncthreads();
    }
    if (c == 0) bc[o] = b2[o] + red[0];
  }
}

// ---------------------------------------------------------------------------
// proj1: 256 thr, grid (313,2). 64 rows x 192 outs (3 internal 64-out tiles).
// ---------------------------------------------------------------------------
__global__ __launch_bounds__(256) void proj1_kernel(
    const float* __restrict__ query, const float* __restrict__ qpos,
    const __hip_bfloat16* __restrict__ Wcat, const float* __restrict__ bcat,
    __hip_bfloat16* __restrict__ value, __hip_bfloat16* __restrict__ offb,
    float* __restrict__ attnb) {
  __shared__ __hip_bfloat16 qa[64][128];
  __shared__ __hip_bfloat16 wb[64][128];
  const int t = threadIdx.x;
  const int r0 = blockIdx.x * 64;

#pragma unroll
  for (int i = 0; i < 4; ++i) {
    int lin = t + 256 * i;
    int r = lin >> 4, g = lin & 15;
    int c = g << 3;
    float4 v0 = make_float4(0.f, 0.f, 0.f, 0.f);
    float4 v1 = make_float4(0.f, 0.f, 0.f, 0.f);
    if (r0 + r < MROWS) {
      const float* p = query + (size_t)(r0 + r) * CDIM + c;
      v0 = *(const float4*)p;
      v1 = *(const float4*)(p + 4);
      const float* p2 = qpos + (size_t)(r0 + r) * CDIM + c;
      float4 u0 = *(const float4*)p2;
      float4 u1 = *(const float4*)(p2 + 4);
      v0.x += u0.x; v0.y += u0.y; v0.z += u0.z; v0.w += u0.w;
      v1.x += u1.x; v1.y += u1.y; v1.z += u1.z; v1.w += u1.w;
    }
    __hip_bfloat16* dst = &qa[r][(g ^ (r & 7)) << 3];
    dst[0] = __float2bfloat16(v0.x); dst[1] = __float2bfloat16(v0.y);
    dst[2] = __float2bfloat16(v0.z); dst[3] = __float2bfloat16(v0.w);
    dst[4] = __float2bfloat16(v1.x); dst[5] = __float2bfloat16(v1.y);
    dst[6] = __float2bfloat16(v1.z); dst[7] = __float2bfloat16(v1.w);
  }
  __syncthreads();

  const int wid = t >> 6;
  const int lane = t & 63;
  const int wr = (wid >> 1) * 32;
  const int wc = (wid & 1) * 32;
  const int lrow = lane & 15;
  const int lk = lane >> 4;

  short8v afr[4][2];
  {
    int ra0 = wr + lrow, ra1 = wr + 16 + lrow;
#pragma unroll
    for (int kk = 0; kk < 4; ++kk) {
      int gb = kk * 4 + lk;
      afr[kk][0] = *(const short8v*)&qa[ra0][(gb ^ (ra0 & 7)) << 3];
      afr[kk][1] = *(const short8v*)&qa[ra1][(gb ^ (ra1 & 7)) << 3];
    }
  }

  for (int ti = 0; ti < 3; ++ti) {
    const int ot = blockIdx.y * 192 + ti * 64;
    __syncthreads();
#pragma unroll
    for (int i = 0; i < 4; ++i) {
      int lin = t + 256 * i;
      int r = lin >> 4, g = lin & 15;
      short8v w = *(const short8v*)(Wcat + (size_t)(ot + r) * 128 + (g << 3));
      *(short8v*)&wb[r][(g ^ (r & 7)) << 3] = w;
    }
    __syncthreads();

    f32x4 acc[2][2];
#pragma unroll
    for (int mi = 0; mi < 2; ++mi)
#pragma unroll
      for (int ni = 0; ni < 2; ++ni) acc[mi][ni] = (f32x4)(0.f);

#pragma unroll
    for (int kk = 0; kk < 4; ++kk) {
      const int gb = kk * 4 + lk;
      int rb0 = wc + lrow, rb1 = wc + 16 + lrow;
      short8v b0 = *(const short8v*)&wb[rb0][(gb ^ (rb0 & 7)) << 3];
      short8v b1 = *(const short8v*)&wb[rb1][(gb ^ (rb1 & 7)) << 3];
      acc[0][0] = __builtin_amdgcn_mfma_f32_16x16x32_bf16(afr[kk][0], b0, acc[0][0], 0, 0, 0);
      acc[0][1] = __builtin_amdgcn_mfma_f32_16x16x32_bf16(afr[kk][0], b1, acc[0][1], 0, 0, 0);
      acc[1][0] = __builtin_amdgcn_mfma_f32_16x16x32_bf16(afr[kk][1], b0, acc[1][0], 0, 0, 0);
      acc[1][1] = __builtin_amdgcn_mfma_f32_16x16x32_bf16(afr[kk][1], b1, acc[1][1], 0, 0, 0);
    }

#pragma unroll
    for (int mi = 0; mi < 2; ++mi) {
#pragma unroll
      for (int ni = 0; ni < 2; ++ni) {
#pragma unroll
        for (int reg = 0; reg < 4; ++reg) {
          int r = r0 + wr + mi * 16 + (lane >> 4) * 4 + reg;
          int o = ot + wc + ni * 16 + (lane & 15);
          if (r >= MROWS) continue;
          float v = acc[mi][ni][reg] + bcat[o];
          int b = r >= NTOK ? 1 : 0;
          int n = r - b * NTOK;
          if (o < 128) {
            int h = o >> 5, rem = o & 31;
            value[(((size_t)b * NHEAD + h) * NTOK + n) * 32 + rem] =
                __float2bfloat16(v);
          } else {
            int h = (o - 128) >> 6, k = (o - 128) & 63;
            size_t base = ((size_t)(b * NHEAD + h) * NTOK + n);
            if (k < 40) {
              offb[base * 40 + k] = __float2bfloat16(v);
            } else if (k < 60) {
              attnb[base * 20 + (k - 40)] = v;
            }
          }
        }
      }
    }
  }
}

// ---------------------------------------------------------------------------
// proj2: 256 thr, grid (313,2). out = A@Wc^T + bc + resid (Wc prefolded).
// ---------------------------------------------------------------------------
__global__ __launch_bounds__(256) void proj2_kernel(
    const __hip_bfloat16* __restrict__ outat,
    const __hip_bfloat16* __restrict__ Wc_bf, const float* __restrict__ bc,
    const float* __restrict__ resid, float* __restrict__ out) {
  __shared__ __hip_bfloat16 qa[64][128];
  __shared__ __hip_bfloat16 wb[64][128];
  const int t = threadIdx.x;
  const int r0 = blockIdx.x * 64;
  const int ot = blockIdx.y * 64;

#pragma unroll
  for (int i = 0; i < 4; ++i) {
    int lin = t + 256 * i;
    int r = lin >> 4, g = lin & 15;
    short8v v = (short8v)(short)0;
    if (r0 + r < MROWS)
      v = *(const short8v*)(outat + (size_t)(r0 + r) * CDIM + (g << 3));
    *(short8v*)&qa[r][(g ^ (r & 7)) << 3] = v;
  }
#pragma unroll
  for (int i = 0; i < 4; ++i) {
    int lin = t + 256 * i;
    int r = lin >> 4, g = lin & 15;
    short8v w = *(const short8v*)(Wc_bf + (size_t)(ot + r) * 128 + (g << 3));
    *(short8v*)&wb[r][(g ^ (r & 7)) << 3] = w;
  }
  __syncthreads();

  const int wid = t >> 6;
  const int lane = t & 63;
  const int wr = (wid >> 1) * 32;
  const int wc = (wid & 1) * 32;
  const int lrow = lane & 15;
  const int lk = lane >> 4;

  f32x4 acc[2][2];
#pragma unroll
  for (int mi = 0; mi < 2; ++mi)
#pragma unroll
    for (int ni = 0; ni < 2; ++ni) acc[mi][ni] = (f32x4)(0.f);

#pragma unroll
  for (int kk = 0; kk < 4; ++kk) {
    const int gb = kk * 4 + lk;
    int ra0 = wr + lrow, ra1 = wr + 16 + lrow;
    int rb0 = wc + lrow, rb1 = wc + 16 + lrow;
    short8v a0 = *(const short8v*)&qa[ra0][(gb ^ (ra0 & 7)) << 3];
    short8v a1 = *(const short8v*)&qa[ra1][(gb ^ (ra1 & 7)) << 3];
    short8v b0 = *(const short8v*)&wb[rb0][(gb ^ (rb0 & 7)) << 3];
    short8v b1 = *(const short8v*)&wb[rb1][(gb ^ (rb1 & 7)) << 3];
    acc[0][0] = __builtin_amdgcn_mfma_f32_16x16x32_bf16(a0, b0, acc[0][0], 0, 0, 0);
    acc[0][1] = __builtin_amdgcn_mfma_f32_16x16x32_bf16(a0, b1, acc[0][1], 0, 0, 0);
    acc[1][0] = __builtin_amdgcn_mfma_f32_16x16x32_bf16(a1, b0, acc[1][0], 0, 0, 0);
    acc[1][1] = __builtin_amdgcn_mfma_f32_16x16x32_bf16(a1, b1, acc[1][1], 0, 0, 0);
  }

#pragma unroll
  for (int mi = 0; mi < 2; ++mi) {
#pragma unroll
    for (int ni = 0; ni < 2; ++ni) {
#pragma unroll
      for (int reg = 0; reg < 4; ++reg) {
        int r = r0 + wr + mi * 16 + (lane >> 4) * 4 + reg;
        int o = ot + wc + ni * 16 + (lane & 15);
        if (r >= MROWS) continue;
        out[(size_t)r * CDIM + o] =
            acc[mi][ni][reg] + bc[o] + resid[(size_t)r * CDIM + o];
      }
    }
  }
}

// ---------------------------------------------------------------------------
// Sampling with BRANCH-FREE hot loop. Out-of-patch points get weight 0 and
// clamped address (v_cndmask) in the hot loop; their bit goes into a mask
// and a deferred fallback loop after the hot loop (one s_cbranch_execz,
// never taken with this data) handles them exactly via global gathers.
// This removes per-point control flow so the scheduler can pipeline all
// 80 ds_read_b128s of the unrolled loop.
// ---------------------------------------------------------------------------
__global__ __launch_bounds__(256) void sample_kernel(
    const __hip_bfloat16* __restrict__ value,
    const __hip_bfloat16* __restrict__ off, const float* __restrict__ attn,
    __hip_bfloat16* __restrict__ outat) {
  const int s = blockIdx.x & 7;
  const int pidx = blockIdx.x >> 3;
  const int PI = pidx % NPATCH, PJ = pidx / NPATCH;
  const int I0 = PI * PTOK, J0 = PJ * PTOK;
  const int b = s >> 2, h = s & 3;

  __shared__ __hip_bfloat16 patch[PDIM * PDIM][CELLPAD];
  const __hip_bfloat16* vglob = value + (size_t)s * NTOK * DHEAD;

  // hoisted per-token loads (issued before staging so latency hides)
  const int dl = threadIdx.x & 3;
  const int tok = threadIdx.x >> 2;
  const int li = tok & 7, lj = tok >> 3;
  const int i = I0 + li, j = J0 + lj;
  const bool tv = (i < HWDIM) && (j < HWDIM);
  const int n = tv ? (i * HWDIM + j) : 0;
  union { int4 v4[5]; unsigned u[20]; } of;
  union { float4 v4[5]; float f[20]; } at;
  {
    const int4* o4 = (const int4*)(off + ((size_t)s * NTOK + n) * 40);
    const float4* a4 = (const float4*)(attn + ((size_t)s * NTOK + n) * 20);
#pragma unroll
    for (int q = 0; q < 5; ++q) of.v4[q] = o4[q];
#pragma unroll
    for (int q = 0; q < 5; ++q) at.v4[q] = a4[q];
  }

  // stage patch: 256 cells x 64B, zeros outside image
#pragma unroll
  for (int it = 0; it < 4; ++it) {
    int lin = threadIdx.x + 256 * it;
    int cell = lin >> 2, part = lin & 3;
    int py = cell >> 4, px = cell & 15;
    int gy = J0 - PHALO + py;
    int gx = I0 - PHALO + px;
    short8v v = (short8v)(short)0;
    if (gy >= 0 && gy < HWDIM && gx >= 0 && gx < HWDIM)
      v = *(const short8v*)(vglob + ((size_t)(gy * HWDIM + gx)) * DHEAD +
                            part * 8);
    *(short8v*)&patch[cell][part * 8] = v;
  }
  __syncthreads();

  if (!tv) return;

  float ssum = 0.f;
#pragma unroll
  for (int p = 0; p < NPNT; ++p) {
    at.f[p] = __expf(at.f[p]);
    ssum += at.f[p];
  }
  const float inv = 1.f / ssum;

  const float fi = (float)i, fj = (float)j;
  f32x4 c0a = (f32x4)(0.f), c0b = (f32x4)(0.f);
  f32x4 c1a = (f32x4)(0.f), c1b = (f32x4)(0.f);
  f32x4 c2a = (f32x4)(0.f), c2b = (f32x4)(0.f);
  f32x4 c3a = (f32x4)(0.f), c3b = (f32x4)(0.f);
  unsigned oob = 0;  // bitmask of out-of-patch points (deferred)
#pragma unroll
  for (int p = 0; p < NPNT; ++p) {
    const unsigned up = of.u[p];
    float x = fi + asf(up << 16);
    float y = fj + asf(up & 0xFFFF0000u);
    float x0f = floorf(x), y0f = floorf(y);
    int ix0 = (int)x0f, iy0 = (int)y0f;
    int ly = iy0 - (J0 - PHALO);
    int lx = ix0 - (I0 - PHALO);
    const bool ok = ((unsigned)ly <= PDIM - 2) & ((unsigned)lx <= PDIM - 2);
    oob |= (ok ? 0u : 1u) << p;
    const float aw = ok ? at.f[p] : 0.f;          // cndmask, no branch
    const int cell = ok ? (ly * PDIM + lx) : 0;   // clamped address
    float wx1 = x - x0f, wy1 = y - y0f;
    float wx0 = 1.f - wx1, wy0 = 1.f - wy1;
    float wya = aw * wy0, wyb = aw * wy1;
    float w00 = wya * wx0, w01 = wya * wx1;
    float w10 = wyb * wx0, w11 = wyb * wx1;
    const __hip_bfloat16* pb = &patch[cell][dl * 8];
    acc_cell(pb, w00, c0a, c0b);
    acc_cell(pb + CELLPAD, w01, c1a, c1b);
    acc_cell(pb + PDIM * CELLPAD, w10, c2a, c2b);
    acc_cell(pb + PDIM * CELLPAD + CELLPAD, w11, c3a, c3b);
  }

  // deferred rare fallback: exact handling of out-of-patch points
  if (oob) {
    for (int p = 0; p < NPNT; ++p) {
      if (!(oob & (1u << p))) continue;
      const unsigned up = of.u[p];
      float x = fi + asf(up << 16);
      float y = fj + asf(up & 0xFFFF0000u);
      float aw = at.f[p];
      float x0f = floorf(x), y0f = floorf(y);
      int ix0 = (int)x0f, iy0 = (int)y0f;
      float wx1 = x - x0f, wy1 = y - y0f;
      float wx0 = 1.f - wx1, wy0 = 1.f - wy1;
      float wgt[4] = {aw * wy0 * wx0, aw * wy0 * wx1, aw * wy1 * wx0,
                      aw * wy1 * wx1};
#pragma unroll
      for (int cy = 0; cy < 2; ++cy) {
        int iy = iy0 + cy;
        if (iy < 0 || iy >= HWDIM) continue;
#pragma unroll
        for (int cx = 0; cx < 2; ++cx) {
          int ix = ix0 + cx;
          if (ix < 0 || ix >= HWDIM) continue;
          acc_cell(vglob + ((size_t)(iy * HWDIM + ix)) * DHEAD + dl * 8,
                   wgt[cy * 2 + cx], c0a, c0b);
        }
      }
    }
  }

  f32x4 a0 = (c0a + c1a) + (c2a + c3a);
  f32x4 a1 = (c0b + c1b) + (c2b + c3b);

  union { short8v v8; __hip_bfloat16 hh[8]; } o;
#pragma unroll
  for (int k = 0; k < 4; ++k) {
    o.hh[k] = __float2bfloat16(a0[k] * inv);
    o.hh[4 + k] = __float2bfloat16(a1[k] * inv);
  }
  *(short8v*)(outat + ((size_t)b * NTOK + n) * CDIM + h * DHEAD + dl * 8) =
      o.v8;
}

extern "C" void kernel_launch(void* const* d_in, const int* in_sizes, int n_in,
                              void* d_out, int out_size, void* d_ws,
                              size_t ws_size, hipStream_t stream) {
  const float* query = (const float*)d_in[0];
  const float* query_pos = (const float*)d_in[1];
  const float* W_val = (const float*)d_in[2];
  const float* b_val = (const float*)d_in[3];
  const float* W_off = (const float*)d_in[4];
  const float* b_off = (const float*)d_in[5];
  const float* W_attn = (const float*)d_in[6];
  const float* b_attn = (const float*)d_in[7];
  const float* W_out1 = (const float*)d_in[8];
  const float* b_out1 = (const float*)d_in[9];
  const float* W_out2 = (const float*)d_in[10];
  const float* b_out2 = (const float*)d_in[11];
  float* out = (float*)d_out;

  char* ws = (char*)d_ws;
  __hip_bfloat16* value = (__hip_bfloat16*)ws;  // (B*NH,N,32) bf16
  ws += (size_t)MROWS * CDIM * 2;
  __hip_bfloat16* offb = (__hip_bfloat16*)ws;   // (B*NH,N,40) bf16
  ws += (size_t)MROWS * 160 * 2;
  float* attnb = (float*)ws;                    // (B*NH,N,20) f32
  ws += (size_t)MROWS * 80 * 4;
  __hip_bfloat16* outat = (__hip_bfloat16*)ws;  // (B,N,C) bf16
  ws += (size_t)MROWS * CDIM * 2;
  float* bcat = (float*)ws; ws += OPAD * 4;
  float* bc = (float*)ws; ws += 128 * 4;
  __hip_bfloat16* Wcat = (__hip_bfloat16*)ws; ws += (size_t)OPAD * 128 * 2;
  __hip_bfloat16* Wc_bf = (__hip_bfloat16*)ws;

  prep_kernel<<<OPAD + 128, 128, 0, stream>>>(
      W_val, b_val, W_off, b_off, W_attn, b_attn, W_out1, b_out1, W_out2,
      b_out2, Wcat, bcat, Wc_bf, bc);

  proj1_kernel<<<dim3(313, 2), 256, 0, stream>>>(query, query_pos, Wcat, bcat,
                                                 value, offb, attnb);

  sample_kernel<<<8 * NPATCH * NPATCH, 256, 0, stream>>>(value, offb, attnb,
                                                         outat);

  proj2_kernel<<<dim3(313, 2), 256, 0, stream>>>(outat, Wc_bf, bc, query, out);
}

// Round 15
// 63.650 us; speedup vs baseline: 1.3734x; 1.3734x over previous
//
#include <hip/hip_runtime.h>
#include <hip/hip_bf16.h>
#include <math.h>

#define NTOK 10000
#define BATCH 2
#define CDIM 128
#define NHEAD 4
#define NPNT 20
#define DHEAD 32
#define HWDIM 100
#define MROWS (BATCH * NTOK)
#define OPAD 384   // 128 value rows + 4 heads x (40 off + 20 attn + 4 pad)
#define PTOK 8
#define PHALO 4
#define PDIM 16
#define NPATCH 13
#define CELLPAD 40 // bf16 per cell in LDS (stride 80B: 16B-aligned)

typedef __attribute__((ext_vector_type(8))) short short8v;
typedef __attribute__((ext_vector_type(4))) short short4v;
typedef __attribute__((ext_vector_type(4))) float f32x4;

__device__ __forceinline__ float asf(unsigned u) {
  union { unsigned u; float f; } c; c.u = u; return c.f;
}

// unpack 8 bf16 (16B) and accumulate w * g into two f32x4 accumulators
__device__ __forceinline__ void acc_cell(const __hip_bfloat16* p, float w,
                                         f32x4& a0, f32x4& a1) {
  int4 u = *(const int4*)p;
  f32x4 g0, g1;
  g0.x = asf(((unsigned)u.x) << 16); g0.y = asf(((unsigned)u.x) & 0xFFFF0000u);
  g0.z = asf(((unsigned)u.y) << 16); g0.w = asf(((unsigned)u.y) & 0xFFFF0000u);
  g1.x = asf(((unsigned)u.z) << 16); g1.y = asf(((unsigned)u.z) & 0xFFFF0000u);
  g1.z = asf(((unsigned)u.w) << 16); g1.w = asf(((unsigned)u.w) & 0xFFFF0000u);
  a0 += g0 * w;
  a1 += g1 * w;
}

// unpack 4 bf16 (8B) and accumulate w * g into one f32x4 accumulator
__device__ __forceinline__ void acc_cell4(const __hip_bfloat16* p, float w,
                                          f32x4& a0) {
  int2 u = *(const int2*)p;
  f32x4 g;
  g.x = asf(((unsigned)u.x) << 16); g.y = asf(((unsigned)u.x) & 0xFFFF0000u);
  g.z = asf(((unsigned)u.y) << 16); g.w = asf(((unsigned)u.y) & 0xFFFF0000u);
  a0 += g * w;
}

// ---------------------------------------------------------------------------
// prep: blocks [0,384): Wcat row blk (bf16) + bcat[blk].
//   row < 128: W_val row. row in [128,384): h=(row-128)>>6, k=(row-128)&63:
//   k<40 -> W_off[h*40+k]; 40<=k<60 -> W_attn[h*20+k-40]; else zero pad.
// blocks [384,512): fold Wc = W2@W1 row -> Wc_bf, bc (for proj2).
// ---------------------------------------------------------------------------
__global__ __launch_bounds__(128) void prep_kernel(
    const float* __restrict__ W_val, const float* __restrict__ b_val,
    const float* __restrict__ W_off, const float* __restrict__ b_off,
    const float* __restrict__ W_attn, const float* __restrict__ b_attn,
    const float* __restrict__ W1, const float* __restrict__ b1,
    const float* __restrict__ W2, const float* __restrict__ b2,
    __hip_bfloat16* __restrict__ Wcat, float* __restrict__ bcat,
    __hip_bfloat16* __restrict__ Wc_bf, float* __restrict__ bc) {
  __shared__ float w2row[128];
  __shared__ float red[128];
  const int blk = blockIdx.x, c = threadIdx.x;
  if (blk < OPAD) {
    float v = 0.f, bv = 0.f;
    if (blk < 128) {
      v = W_val[blk * 128 + c]; bv = b_val[blk];
    } else {
      int h = (blk - 128) >> 6, k = (blk - 128) & 63;
      if (k < 40) { v = W_off[(h * 40 + k) * 128 + c]; bv = b_off[h * 40 + k]; }
      else if (k < 60) { v = W_attn[(h * 20 + k - 40) * 128 + c]; bv = b_attn[h * 20 + k - 40]; }
    }
    Wcat[(size_t)blk * 128 + c] = __float2bfloat16(v);
    if (c == 0) bcat[blk] = bv;
  } else {
    const int o = blk - OPAD;  // 0..127
    w2row[c] = W2[o * 128 + c];
    __syncthreads();
    float acc = 0.f;
    for (int k = 0; k < 128; ++k) acc += w2row[k] * W1[k * 128 + c];
    Wc_bf[(size_t)o * 128 + c] = __float2bfloat16(acc);
    red[c] = w2row[c] * b1[c];
    __syncthreads();
    for (int s = 64; s > 0; s >>= 1) {
      if (c < s) red[c] += red[c + s];
      __syncthreads();
    }
    if (c == 0) bc[o] = b2[o] + red[0];
  }
}

// ---------------------------------------------------------------------------
// proj1: 256 thr, grid (313,2). 64 rows x 192 outs (3 internal 64-out tiles).
// ---------------------------------------------------------------------------
__global__ __launch_bounds__(256) void proj1_kernel(
    const float* __restrict__ query, const float* __restrict__ qpos,
    const __hip_bfloat16* __restrict__ Wcat, const float* __restrict__ bcat,
    __hip_bfloat16* __restrict__ value, __hip_bfloat16* __restrict__ offb,
    float* __restrict__ attnb) {
  __shared__ __hip_bfloat16 qa[64][128];
  __shared__ __hip_bfloat16 wb[64][128];
  const int t = threadIdx.x;
  const int r0 = blockIdx.x * 64;

#pragma unroll
  for (int i = 0; i < 4; ++i) {
    int lin = t + 256 * i;
    int r = lin >> 4, g = lin & 15;
    int c = g << 3;
    float4 v0 = make_float4(0.f, 0.f, 0.f, 0.f);
    float4 v1 = make_float4(0.f, 0.f, 0.f, 0.f);
    if (r0 + r < MROWS) {
      const float* p = query + (size_t)(r0 + r) * CDIM + c;
      v0 = *(const float4*)p;
      v1 = *(const float4*)(p + 4);
      const float* p2 = qpos + (size_t)(r0 + r) * CDIM + c;
      float4 u0 = *(const float4*)p2;
      float4 u1 = *(const float4*)(p2 + 4);
      v0.x += u0.x; v0.y += u0.y; v0.z += u0.z; v0.w += u0.w;
      v1.x += u1.x; v1.y += u1.y; v1.z += u1.z; v1.w += u1.w;
    }
    __hip_bfloat16* dst = &qa[r][(g ^ (r & 7)) << 3];
    dst[0] = __float2bfloat16(v0.x); dst[1] = __float2bfloat16(v0.y);
    dst[2] = __float2bfloat16(v0.z); dst[3] = __float2bfloat16(v0.w);
    dst[4] = __float2bfloat16(v1.x); dst[5] = __float2bfloat16(v1.y);
    dst[6] = __float2bfloat16(v1.z); dst[7] = __float2bfloat16(v1.w);
  }
  __syncthreads();

  const int wid = t >> 6;
  const int lane = t & 63;
  const int wr = (wid >> 1) * 32;
  const int wc = (wid & 1) * 32;
  const int lrow = lane & 15;
  const int lk = lane >> 4;

  short8v afr[4][2];
  {
    int ra0 = wr + lrow, ra1 = wr + 16 + lrow;
#pragma unroll
    for (int kk = 0; kk < 4; ++kk) {
      int gb = kk * 4 + lk;
      afr[kk][0] = *(const short8v*)&qa[ra0][(gb ^ (ra0 & 7)) << 3];
      afr[kk][1] = *(const short8v*)&qa[ra1][(gb ^ (ra1 & 7)) << 3];
    }
  }

  for (int ti = 0; ti < 3; ++ti) {
    const int ot = blockIdx.y * 192 + ti * 64;
    __syncthreads();
#pragma unroll
    for (int i = 0; i < 4; ++i) {
      int lin = t + 256 * i;
      int r = lin >> 4, g = lin & 15;
      short8v w = *(const short8v*)(Wcat + (size_t)(ot + r) * 128 + (g << 3));
      *(short8v*)&wb[r][(g ^ (r & 7)) << 3] = w;
    }
    __syncthreads();

    f32x4 acc[2][2];
#pragma unroll
    for (int mi = 0; mi < 2; ++mi)
#pragma unroll
      for (int ni = 0; ni < 2; ++ni) acc[mi][ni] = (f32x4)(0.f);

#pragma unroll
    for (int kk = 0; kk < 4; ++kk) {
      const int gb = kk * 4 + lk;
      int rb0 = wc + lrow, rb1 = wc + 16 + lrow;
      short8v b0 = *(const short8v*)&wb[rb0][(gb ^ (rb0 & 7)) << 3];
      short8v b1 = *(const short8v*)&wb[rb1][(gb ^ (rb1 & 7)) << 3];
      acc[0][0] = __builtin_amdgcn_mfma_f32_16x16x32_bf16(afr[kk][0], b0, acc[0][0], 0, 0, 0);
      acc[0][1] = __builtin_amdgcn_mfma_f32_16x16x32_bf16(afr[kk][0], b1, acc[0][1], 0, 0, 0);
      acc[1][0] = __builtin_amdgcn_mfma_f32_16x16x32_bf16(afr[kk][1], b0, acc[1][0], 0, 0, 0);
      acc[1][1] = __builtin_amdgcn_mfma_f32_16x16x32_bf16(afr[kk][1], b1, acc[1][1], 0, 0, 0);
    }

#pragma unroll
    for (int mi = 0; mi < 2; ++mi) {
#pragma unroll
      for (int ni = 0; ni < 2; ++ni) {
#pragma unroll
        for (int reg = 0; reg < 4; ++reg) {
          int r = r0 + wr + mi * 16 + (lane >> 4) * 4 + reg;
          int o = ot + wc + ni * 16 + (lane & 15);
          if (r >= MROWS) continue;
          float v = acc[mi][ni][reg] + bcat[o];
          int b = r >= NTOK ? 1 : 0;
          int n = r - b * NTOK;
          if (o < 128) {
            int h = o >> 5, rem = o & 31;
            value[(((size_t)b * NHEAD + h) * NTOK + n) * 32 + rem] =
                __float2bfloat16(v);
          } else {
            int h = (o - 128) >> 6, k = (o - 128) & 63;
            size_t base = ((size_t)(b * NHEAD + h) * NTOK + n);
            if (k < 40) {
              offb[base * 40 + k] = __float2bfloat16(v);
            } else if (k < 60) {
              attnb[base * 20 + (k - 40)] = v;
            }
          }
        }
      }
    }
  }
}

// ---------------------------------------------------------------------------
// proj2: 256 thr, grid (313,2). out = A@Wc^T + bc + resid (Wc prefolded).
// ---------------------------------------------------------------------------
__global__ __launch_bounds__(256) void proj2_kernel(
    const __hip_bfloat16* __restrict__ outat,
    const __hip_bfloat16* __restrict__ Wc_bf, const float* __restrict__ bc,
    const float* __restrict__ resid, float* __restrict__ out) {
  __shared__ __hip_bfloat16 qa[64][128];
  __shared__ __hip_bfloat16 wb[64][128];
  const int t = threadIdx.x;
  const int r0 = blockIdx.x * 64;
  const int ot = blockIdx.y * 64;

#pragma unroll
  for (int i = 0; i < 4; ++i) {
    int lin = t + 256 * i;
    int r = lin >> 4, g = lin & 15;
    short8v v = (short8v)(short)0;
    if (r0 + r < MROWS)
      v = *(const short8v*)(outat + (size_t)(r0 + r) * CDIM + (g << 3));
    *(short8v*)&qa[r][(g ^ (r & 7)) << 3] = v;
  }
#pragma unroll
  for (int i = 0; i < 4; ++i) {
    int lin = t + 256 * i;
    int r = lin >> 4, g = lin & 15;
    short8v w = *(const short8v*)(Wc_bf + (size_t)(ot + r) * 128 + (g << 3));
    *(short8v*)&wb[r][(g ^ (r & 7)) << 3] = w;
  }
  __syncthreads();

  const int wid = t >> 6;
  const int lane = t & 63;
  const int wr = (wid >> 1) * 32;
  const int wc = (wid & 1) * 32;
  const int lrow = lane & 15;
  const int lk = lane >> 4;

  f32x4 acc[2][2];
#pragma unroll
  for (int mi = 0; mi < 2; ++mi)
#pragma unroll
    for (int ni = 0; ni < 2; ++ni) acc[mi][ni] = (f32x4)(0.f);

#pragma unroll
  for (int kk = 0; kk < 4; ++kk) {
    const int gb = kk * 4 + lk;
    int ra0 = wr + lrow, ra1 = wr + 16 + lrow;
    int rb0 = wc + lrow, rb1 = wc + 16 + lrow;
    short8v a0 = *(const short8v*)&qa[ra0][(gb ^ (ra0 & 7)) << 3];
    short8v a1 = *(const short8v*)&qa[ra1][(gb ^ (ra1 & 7)) << 3];
    short8v b0 = *(const short8v*)&wb[rb0][(gb ^ (rb0 & 7)) << 3];
    short8v b1 = *(const short8v*)&wb[rb1][(gb ^ (rb1 & 7)) << 3];
    acc[0][0] = __builtin_amdgcn_mfma_f32_16x16x32_bf16(a0, b0, acc[0][0], 0, 0, 0);
    acc[0][1] = __builtin_amdgcn_mfma_f32_16x16x32_bf16(a0, b1, acc[0][1], 0, 0, 0);
    acc[1][0] = __builtin_amdgcn_mfma_f32_16x16x32_bf16(a1, b0, acc[1][0], 0, 0, 0);
    acc[1][1] = __builtin_amdgcn_mfma_f32_16x16x32_bf16(a1, b1, acc[1][1], 0, 0, 0);
  }

#pragma unroll
  for (int mi = 0; mi < 2; ++mi) {
#pragma unroll
    for (int ni = 0; ni < 2; ++ni) {
#pragma unroll
      for (int reg = 0; reg < 4; ++reg) {
        int r = r0 + wr + mi * 16 + (lane >> 4) * 4 + reg;
        int o = ot + wc + ni * 16 + (lane & 15);
        if (r >= MROWS) continue;
        out[(size_t)r * CDIM + o] =
            acc[mi][ni][reg] + bc[o] + resid[(size_t)r * CDIM + o];
      }
    }
  }
}

// ---------------------------------------------------------------------------
// Sampling: 512 threads = 8 waves/block (up from 4) for 32-wave/CU occupancy.
// 8 lanes/token (dl = t&7, 4 dims each), 64 tokens/block, same 20.5 KB bf16
// patch. Per corner one ds_read_b64 + 4 unpack + 4 FMA. Hoisted off/attn
// loads; branchy (VGPR-safe) in-patch path with rare global fallback;
// deferred softmax normalization.
// ---------------------------------------------------------------------------
__global__ __launch_bounds__(512) void sample_kernel(
    const __hip_bfloat16* __restrict__ value,
    const __hip_bfloat16* __restrict__ off, const float* __restrict__ attn,
    __hip_bfloat16* __restrict__ outat) {
  const int s = blockIdx.x & 7;
  const int pidx = blockIdx.x >> 3;
  const int PI = pidx % NPATCH, PJ = pidx / NPATCH;
  const int I0 = PI * PTOK, J0 = PJ * PTOK;
  const int b = s >> 2, h = s & 3;

  __shared__ __hip_bfloat16 patch[PDIM * PDIM][CELLPAD];
  const __hip_bfloat16* vglob = value + (size_t)s * NTOK * DHEAD;

  // hoisted per-token loads (issued before staging so latency hides)
  const int dl = threadIdx.x & 7;    // 4 dims at dl*4
  const int tok = threadIdx.x >> 3;  // 0..63
  const int li = tok & 7, lj = tok >> 3;
  const int i = I0 + li, j = J0 + lj;
  const bool tv = (i < HWDIM) && (j < HWDIM);
  const int n = tv ? (i * HWDIM + j) : 0;
  union { int4 v4[5]; unsigned u[20]; } of;
  union { float4 v4[5]; float f[20]; } at;
  {
    const int4* o4 = (const int4*)(off + ((size_t)s * NTOK + n) * 40);
    const float4* a4 = (const float4*)(attn + ((size_t)s * NTOK + n) * 20);
#pragma unroll
    for (int q = 0; q < 5; ++q) of.v4[q] = o4[q];
#pragma unroll
    for (int q = 0; q < 5; ++q) at.v4[q] = a4[q];
  }

  // stage patch: 1024 granules over 512 threads (2 iters), zeros outside
#pragma unroll
  for (int it = 0; it < 2; ++it) {
    int lin = threadIdx.x + 512 * it;
    int cell = lin >> 2, part = lin & 3;
    int py = cell >> 4, px = cell & 15;
    int gy = J0 - PHALO + py;
    int gx = I0 - PHALO + px;
    short8v v = (short8v)(short)0;
    if (gy >= 0 && gy < HWDIM && gx >= 0 && gx < HWDIM)
      v = *(const short8v*)(vglob + ((size_t)(gy * HWDIM + gx)) * DHEAD +
                            part * 8);
    *(short8v*)&patch[cell][part * 8] = v;
  }
  __syncthreads();

  if (!tv) return;

  float ssum = 0.f;
#pragma unroll
  for (int p = 0; p < NPNT; ++p) {
    at.f[p] = __expf(at.f[p]);
    ssum += at.f[p];
  }
  const float inv = 1.f / ssum;

  const float fi = (float)i, fj = (float)j;
  f32x4 c0 = (f32x4)(0.f), c1 = (f32x4)(0.f);
  f32x4 c2 = (f32x4)(0.f), c3 = (f32x4)(0.f);
#pragma unroll
  for (int p = 0; p < NPNT; ++p) {
    const unsigned up = of.u[p];
    float x = fi + asf(up << 16);
    float y = fj + asf(up & 0xFFFF0000u);
    float aw = at.f[p];
    float x0f = floorf(x), y0f = floorf(y);
    int ix0 = (int)x0f, iy0 = (int)y0f;
    float wx1 = x - x0f, wy1 = y - y0f;
    float wx0 = 1.f - wx1, wy0 = 1.f - wy1;
    float wya = aw * wy0, wyb = aw * wy1;
    float w00 = wya * wx0, w01 = wya * wx1;
    float w10 = wyb * wx0, w11 = wyb * wx1;
    int ly = iy0 - (J0 - PHALO);
    int lx = ix0 - (I0 - PHALO);
    if ((unsigned)ly <= PDIM - 2 && (unsigned)lx <= PDIM - 2) {
      const __hip_bfloat16* pb = &patch[ly * PDIM + lx][dl * 4];
      acc_cell4(pb, w00, c0);
      acc_cell4(pb + CELLPAD, w01, c1);
      acc_cell4(pb + PDIM * CELLPAD, w10, c2);
      acc_cell4(pb + PDIM * CELLPAD + CELLPAD, w11, c3);
    } else {
      float wgt[4] = {w00, w01, w10, w11};
#pragma unroll
      for (int cy = 0; cy < 2; ++cy) {
        int iy = iy0 + cy;
        if (iy < 0 || iy >= HWDIM) continue;
#pragma unroll
        for (int cx = 0; cx < 2; ++cx) {
          int ix = ix0 + cx;
          if (ix < 0 || ix >= HWDIM) continue;
          acc_cell4(vglob + ((size_t)(iy * HWDIM + ix)) * DHEAD + dl * 4,
                    wgt[cy * 2 + cx], c0);
        }
      }
    }
  }
  f32x4 a0 = (c0 + c1) + (c2 + c3);

  union { short4v v4; __hip_bfloat16 hh[4]; } o;
#pragma unroll
  for (int k = 0; k < 4; ++k) o.hh[k] = __float2bfloat16(a0[k] * inv);
  *(short4v*)(outat + ((size_t)b * NTOK + n) * CDIM + h * DHEAD + dl * 4) =
      o.v4;
}

extern "C" void kernel_launch(void* const* d_in, const int* in_sizes, int n_in,
                              void* d_out, int out_size, void* d_ws,
                              size_t ws_size, hipStream_t stream) {
  const float* query = (const float*)d_in[0];
  const float* query_pos = (const float*)d_in[1];
  const float* W_val = (const float*)d_in[2];
  const float* b_val = (const float*)d_in[3];
  const float* W_off = (const float*)d_in[4];
  const float* b_off = (const float*)d_in[5];
  const float* W_attn = (const float*)d_in[6];
  const float* b_attn = (const float*)d_in[7];
  const float* W_out1 = (const float*)d_in[8];
  const float* b_out1 = (const float*)d_in[9];
  const float* W_out2 = (const float*)d_in[10];
  const float* b_out2 = (const float*)d_in[11];
  float* out = (float*)d_out;

  char* ws = (char*)d_ws;
  __hip_bfloat16* value = (__hip_bfloat16*)ws;  // (B*NH,N,32) bf16
  ws += (size_t)MROWS * CDIM * 2;
  __hip_bfloat16* offb = (__hip_bfloat16*)ws;   // (B*NH,N,40) bf16
  ws += (size_t)MROWS * 160 * 2;
  float* attnb = (float*)ws;                    // (B*NH,N,20) f32
  ws += (size_t)MROWS * 80 * 4;
  __hip_bfloat16* outat = (__hip_bfloat16*)ws;  // (B,N,C) bf16
  ws += (size_t)MROWS * CDIM * 2;
  float* bcat = (float*)ws; ws += OPAD * 4;
  float* bc = (float*)ws; ws += 128 * 4;
  __hip_bfloat16* Wcat = (__hip_bfloat16*)ws; ws += (size_t)OPAD * 128 * 2;
  __hip_bfloat16* Wc_bf = (__hip_bfloat16*)ws;

  prep_kernel<<<OPAD + 128, 128, 0, stream>>>(
      W_val, b_val, W_off, b_off, W_attn, b_attn, W_out1, b_out1, W_out2,
      b_out2, Wcat, bcat, Wc_bf, bc);

  proj1_kernel<<<dim3(313, 2), 256, 0, stream>>>(query, query_pos, Wcat, bcat,
                                                 value, offb, attnb);

  sample_kernel<<<8 * NPATCH * NPATCH, 512, 0, stream>>>(value, offb, attnb,
                                                         outat);

  proj2_kernel<<<dim3(313, 2), 256, 0, stream>>>(outat, Wc_bf, bc, query, out);
}

// Round 16
// 58.831 us; speedup vs baseline: 1.4859x; 1.0819x over previous
//
#include <hip/hip_runtime.h>
#include <hip/hip_bf16.h>
#include <math.h>

#define NTOK 10000
#define BATCH 2
#define CDIM 128
#define NHEAD 4
#define NPNT 20
#define DHEAD 32
#define HWDIM 100
#define MROWS (BATCH * NTOK)
#define OPAD 384   // 128 value rows + 4 heads x (40 off + 20 attn + 4 pad)
#define PHALO 4
#define TTILE 4    // 4x4 tokens per patch
#define SPD 12     // TTILE + 2*PHALO
#define NPT 25     // 100 / TTILE
#define CELLPAD 40 // bf16 per cell in LDS (stride 80B: 16B-aligned)

typedef __attribute__((ext_vector_type(8))) short short8v;
typedef __attribute__((ext_vector_type(4))) short short4v;
typedef __attribute__((ext_vector_type(4))) float f32x4;

__device__ __forceinline__ float asf(unsigned u) {
  union { unsigned u; float f; } c; c.u = u; return c.f;
}

// unpack 8 bf16 (16B) and accumulate w * g into two f32x4 accumulators
__device__ __forceinline__ void acc_cell(const __hip_bfloat16* p, float w,
                                         f32x4& a0, f32x4& a1) {
  int4 u = *(const int4*)p;
  f32x4 g0, g1;
  g0.x = asf(((unsigned)u.x) << 16); g0.y = asf(((unsigned)u.x) & 0xFFFF0000u);
  g0.z = asf(((unsigned)u.y) << 16); g0.w = asf(((unsigned)u.y) & 0xFFFF0000u);
  g1.x = asf(((unsigned)u.z) << 16); g1.y = asf(((unsigned)u.z) & 0xFFFF0000u);
  g1.z = asf(((unsigned)u.w) << 16); g1.w = asf(((unsigned)u.w) & 0xFFFF0000u);
  a0 += g0 * w;
  a1 += g1 * w;
}

// ---------------------------------------------------------------------------
// prep: blocks [0,384): Wcat row blk (bf16) + bcat[blk].
//   row < 128: W_val row. row in [128,384): h=(row-128)>>6, k=(row-128)&63:
//   k<40 -> W_off[h*40+k]; 40<=k<60 -> W_attn[h*20+k-40]; else zero pad.
// blocks [384,512): fold Wc = W2@W1 row -> Wc_bf, bc (for proj2).
// ---------------------------------------------------------------------------
__global__ __launch_bounds__(128) void prep_kernel(
    const float* __restrict__ W_val, const float* __restrict__ b_val,
    const float* __restrict__ W_off, const float* __restrict__ b_off,
    const float* __restrict__ W_attn, const float* __restrict__ b_attn,
    const float* __restrict__ W1, const float* __restrict__ b1,
    const float* __restrict__ W2, const float* __restrict__ b2,
    __hip_bfloat16* __restrict__ Wcat, float* __restrict__ bcat,
    __hip_bfloat16* __restrict__ Wc_bf, float* __restrict__ bc) {
  __shared__ float w2row[128];
  __shared__ float red[128];
  const int blk = blockIdx.x, c = threadIdx.x;
  if (blk < OPAD) {
    float v = 0.f, bv = 0.f;
    if (blk < 128) {
      v = W_val[blk * 128 + c]; bv = b_val[blk];
    } else {
      int h = (blk - 128) >> 6, k = (blk - 128) & 63;
      if (k < 40) { v = W_off[(h * 40 + k) * 128 + c]; bv = b_off[h * 40 + k]; }
      else if (k < 60) { v = W_attn[(h * 20 + k - 40) * 128 + c]; bv = b_attn[h * 20 + k - 40]; }
    }
    Wcat[(size_t)blk * 128 + c] = __float2bfloat16(v);
    if (c == 0) bcat[blk] = bv;
  } else {
    const int o = blk - OPAD;  // 0..127
    w2row[c] = W2[o * 128 + c];
    __syncthreads();
    float acc = 0.f;
    for (int k = 0; k < 128; ++k) acc += w2row[k] * W1[k * 128 + c];
    Wc_bf[(size_t)o * 128 + c] = __float2bfloat16(acc);
    red[c] = w2row[c] * b1[c];
    __syncthreads();
    for (int s = 64; s > 0; s >>= 1) {
      if (c < s) red[c] += red[c + s];
      __syncthreads();
    }
    if (c == 0) bc[o] = b2[o] + red[0];
  }
}

// ---------------------------------------------------------------------------
// proj1: 256 thr, grid (313,2). 64 rows x 192 outs (3 internal 64-out tiles).
// ---------------------------------------------------------------------------
__global__ __launch_bounds__(256) void proj1_kernel(
    const float* __restrict__ query, const float* __restrict__ qpos,
    const __hip_bfloat16* __restrict__ Wcat, const float* __restrict__ bcat,
    __hip_bfloat16* __restrict__ value, __hip_bfloat16* __restrict__ offb,
    float* __restrict__ attnb) {
  __shared__ __hip_bfloat16 qa[64][128];
  __shared__ __hip_bfloat16 wb[64][128];
  const int t = threadIdx.x;
  const int r0 = blockIdx.x * 64;

#pragma unroll
  for (int i = 0; i < 4; ++i) {
    int lin = t + 256 * i;
    int r = lin >> 4, g = lin & 15;
    int c = g << 3;
    float4 v0 = make_float4(0.f, 0.f, 0.f, 0.f);
    float4 v1 = make_float4(0.f, 0.f, 0.f, 0.f);
    if (r0 + r < MROWS) {
      const float* p = query + (size_t)(r0 + r) * CDIM + c;
      v0 = *(const float4*)p;
      v1 = *(const float4*)(p + 4);
      const float* p2 = qpos + (size_t)(r0 + r) * CDIM + c;
      float4 u0 = *(const float4*)p2;
      float4 u1 = *(const float4*)(p2 + 4);
      v0.x += u0.x; v0.y += u0.y; v0.z += u0.z; v0.w += u0.w;
      v1.x += u1.x; v1.y += u1.y; v1.z += u1.z; v1.w += u1.w;
    }
    __hip_bfloat16* dst = &qa[r][(g ^ (r & 7)) << 3];
    dst[0] = __float2bfloat16(v0.x); dst[1] = __float2bfloat16(v0.y);
    dst[2] = __float2bfloat16(v0.z); dst[3] = __float2bfloat16(v0.w);
    dst[4] = __float2bfloat16(v1.x); dst[5] = __float2bfloat16(v1.y);
    dst[6] = __float2bfloat16(v1.z); dst[7] = __float2bfloat16(v1.w);
  }
  __syncthreads();

  const int wid = t >> 6;
  const int lane = t & 63;
  const int wr = (wid >> 1) * 32;
  const int wc = (wid & 1) * 32;
  const int lrow = lane & 15;
  const int lk = lane >> 4;

  short8v afr[4][2];
  {
    int ra0 = wr + lrow, ra1 = wr + 16 + lrow;
#pragma unroll
    for (int kk = 0; kk < 4; ++kk) {
      int gb = kk * 4 + lk;
      afr[kk][0] = *(const short8v*)&qa[ra0][(gb ^ (ra0 & 7)) << 3];
      afr[kk][1] = *(const short8v*)&qa[ra1][(gb ^ (ra1 & 7)) << 3];
    }
  }

  for (int ti = 0; ti < 3; ++ti) {
    const int ot = blockIdx.y * 192 + ti * 64;
    __syncthreads();
#pragma unroll
    for (int i = 0; i < 4; ++i) {
      int lin = t + 256 * i;
      int r = lin >> 4, g = lin & 15;
      short8v w = *(const short8v*)(Wcat + (size_t)(ot + r) * 128 + (g << 3));
      *(short8v*)&wb[r][(g ^ (r & 7)) << 3] = w;
    }
    __syncthreads();

    f32x4 acc[2][2];
#pragma unroll
    for (int mi = 0; mi < 2; ++mi)
#pragma unroll
      for (int ni = 0; ni < 2; ++ni) acc[mi][ni] = (f32x4)(0.f);

#pragma unroll
    for (int kk = 0; kk < 4; ++kk) {
      const int gb = kk * 4 + lk;
      int rb0 = wc + lrow, rb1 = wc + 16 + lrow;
      short8v b0 = *(const short8v*)&wb[rb0][(gb ^ (rb0 & 7)) << 3];
      short8v b1 = *(const short8v*)&wb[rb1][(gb ^ (rb1 & 7)) << 3];
      acc[0][0] = __builtin_amdgcn_mfma_f32_16x16x32_bf16(afr[kk][0], b0, acc[0][0], 0, 0, 0);
      acc[0][1] = __builtin_amdgcn_mfma_f32_16x16x32_bf16(afr[kk][0], b1, acc[0][1], 0, 0, 0);
      acc[1][0] = __builtin_amdgcn_mfma_f32_16x16x32_bf16(afr[kk][1], b0, acc[1][0], 0, 0, 0);
      acc[1][1] = __builtin_amdgcn_mfma_f32_16x16x32_bf16(afr[kk][1], b1, acc[1][1], 0, 0, 0);
    }

#pragma unroll
    for (int mi = 0; mi < 2; ++mi) {
#pragma unroll
      for (int ni = 0; ni < 2; ++ni) {
#pragma unroll
        for (int reg = 0; reg < 4; ++reg) {
          int r = r0 + wr + mi * 16 + (lane >> 4) * 4 + reg;
          int o = ot + wc + ni * 16 + (lane & 15);
          if (r >= MROWS) continue;
          float v = acc[mi][ni][reg] + bcat[o];
          int b = r >= NTOK ? 1 : 0;
          int n = r - b * NTOK;
          if (o < 128) {
            int h = o >> 5, rem = o & 31;
            value[(((size_t)b * NHEAD + h) * NTOK + n) * 32 + rem] =
                __float2bfloat16(v);
          } else {
            int h = (o - 128) >> 6, k = (o - 128) & 63;
            size_t base = ((size_t)(b * NHEAD + h) * NTOK + n);
            if (k < 40) {
              offb[base * 40 + k] = __float2bfloat16(v);
            } else if (k < 60) {
              attnb[base * 20 + (k - 40)] = v;
            }
          }
        }
      }
    }
  }
}

// ---------------------------------------------------------------------------
// proj2: 256 thr, grid (313,2). out = A@Wc^T + bc + resid (Wc prefolded).
// ---------------------------------------------------------------------------
__global__ __launch_bounds__(256) void proj2_kernel(
    const __hip_bfloat16* __restrict__ outat,
    const __hip_bfloat16* __restrict__ Wc_bf, const float* __restrict__ bc,
    const float* __restrict__ resid, float* __restrict__ out) {
  __shared__ __hip_bfloat16 qa[64][128];
  __shared__ __hip_bfloat16 wb[64][128];
  const int t = threadIdx.x;
  const int r0 = blockIdx.x * 64;
  const int ot = blockIdx.y * 64;

#pragma unroll
  for (int i = 0; i < 4; ++i) {
    int lin = t + 256 * i;
    int r = lin >> 4, g = lin & 15;
    short8v v = (short8v)(short)0;
    if (r0 + r < MROWS)
      v = *(const short8v*)(outat + (size_t)(r0 + r) * CDIM + (g << 3));
    *(short8v*)&qa[r][(g ^ (r & 7)) << 3] = v;
  }
#pragma unroll
  for (int i = 0; i < 4; ++i) {
    int lin = t + 256 * i;
    int r = lin >> 4, g = lin & 15;
    short8v w = *(const short8v*)(Wc_bf + (size_t)(ot + r) * 128 + (g << 3));
    *(short8v*)&wb[r][(g ^ (r & 7)) << 3] = w;
  }
  __syncthreads();

  const int wid = t >> 6;
  const int lane = t & 63;
  const int wr = (wid >> 1) * 32;
  const int wc = (wid & 1) * 32;
  const int lrow = lane & 15;
  const int lk = lane >> 4;

  f32x4 acc[2][2];
#pragma unroll
  for (int mi = 0; mi < 2; ++mi)
#pragma unroll
    for (int ni = 0; ni < 2; ++ni) acc[mi][ni] = (f32x4)(0.f);

#pragma unroll
  for (int kk = 0; kk < 4; ++kk) {
    const int gb = kk * 4 + lk;
    int ra0 = wr + lrow, ra1 = wr + 16 + lrow;
    int rb0 = wc + lrow, rb1 = wc + 16 + lrow;
    short8v a0 = *(const short8v*)&qa[ra0][(gb ^ (ra0 & 7)) << 3];
    short8v a1 = *(const short8v*)&qa[ra1][(gb ^ (ra1 & 7)) << 3];
    short8v b0 = *(const short8v*)&wb[rb0][(gb ^ (rb0 & 7)) << 3];
    short8v b1 = *(const short8v*)&wb[rb1][(gb ^ (rb1 & 7)) << 3];
    acc[0][0] = __builtin_amdgcn_mfma_f32_16x16x32_bf16(a0, b0, acc[0][0], 0, 0, 0);
    acc[0][1] = __builtin_amdgcn_mfma_f32_16x16x32_bf16(a0, b1, acc[0][1], 0, 0, 0);
    acc[1][0] = __builtin_amdgcn_mfma_f32_16x16x32_bf16(a1, b0, acc[1][0], 0, 0, 0);
    acc[1][1] = __builtin_amdgcn_mfma_f32_16x16x32_bf16(a1, b1, acc[1][1], 0, 0, 0);
  }

#pragma unroll
  for (int mi = 0; mi < 2; ++mi) {
#pragma unroll
    for (int ni = 0; ni < 2; ++ni) {
#pragma unroll
      for (int reg = 0; reg < 4; ++reg) {
        int r = r0 + wr + mi * 16 + (lane >> 4) * 4 + reg;
        int o = ot + wc + ni * 16 + (lane & 15);
        if (r >= MROWS) continue;
        out[(size_t)r * CDIM + o] =
            acc[mi][ni][reg] + bc[o] + resid[(size_t)r * CDIM + o];
      }
    }
  }
}

// ---------------------------------------------------------------------------
// Sampling, point-split: 16 lanes/token = 4 point-groups (5 points each) x
// 4 dim-groups (8 dims each). Per-wave serial chain drops 4x vs the 20-point
// loop; grid 5000 blocks (4x4-token tiles, 12x12 halo patch, 11.5 KB LDS).
// Deferred softmax: each lane exps only its 5 logits; accumulators AND the
// exp-sum are reduced across point-groups with __shfl_xor(4,8). pg==0 lanes
// store. Hoisted off/attn loads; branchy rare global fallback.
// ---------------------------------------------------------------------------
__global__ __launch_bounds__(256) void sample_kernel(
    const __hip_bfloat16* __restrict__ value,
    const __hip_bfloat16* __restrict__ off, const float* __restrict__ attn,
    __hip_bfloat16* __restrict__ outat) {
  const int s = blockIdx.x & 7;
  const int pidx = blockIdx.x >> 3;  // 0..624
  const int PI = pidx % NPT, PJ = pidx / NPT;
  const int I0 = PI * TTILE, J0 = PJ * TTILE;
  const int b = s >> 2, h = s & 3;

  __shared__ __hip_bfloat16 patch[SPD * SPD][CELLPAD];
  const __hip_bfloat16* vglob = value + (size_t)s * NTOK * DHEAD;

  const int t = threadIdx.x;
  const int lane16 = t & 15;
  const int dg = lane16 & 3;   // dim group: 8 dims at dg*8
  const int pg = lane16 >> 2;  // point group: points pg*5 .. pg*5+4
  const int tok = t >> 4;      // 0..15
  const int li = tok & 3, lj = tok >> 2;
  const int i = I0 + li, j = J0 + lj;
  const int n = i * HWDIM + j;

  // hoisted per-lane loads: 5 offset-pairs (u32) + 5 attn logits for this pg
  unsigned ofu[5];
  float atf[5];
  {
    const unsigned* ob =
        (const unsigned*)(off + ((size_t)s * NTOK + n) * 40) + pg * 5;
    const float* ab = attn + ((size_t)s * NTOK + n) * 20 + pg * 5;
#pragma unroll
    for (int k = 0; k < 5; ++k) { ofu[k] = ob[k]; atf[k] = ab[k]; }
  }

  // stage patch: 144 cells x 4 granule-parts = 576 over 256 thr
#pragma unroll
  for (int it = 0; it < 3; ++it) {
    int lin = t + 256 * it;
    if (lin < SPD * SPD * 4) {
      int cell = lin >> 2, part = lin & 3;
      int py = cell / SPD, px = cell - py * SPD;
      int gy = J0 - PHALO + py;
      int gx = I0 - PHALO + px;
      short8v v = (short8v)(short)0;
      if (gy >= 0 && gy < HWDIM && gx >= 0 && gx < HWDIM)
        v = *(const short8v*)(vglob + ((size_t)(gy * HWDIM + gx)) * DHEAD +
                              part * 8);
      *(short8v*)&patch[cell][part * 8] = v;
    }
  }
  __syncthreads();

  float ssum = 0.f;
#pragma unroll
  for (int k = 0; k < 5; ++k) {
    atf[k] = __expf(atf[k]);
    ssum += atf[k];
  }

  const float fi = (float)i, fj = (float)j;
  f32x4 a0 = (f32x4)(0.f), a1 = (f32x4)(0.f);
  f32x4 e0 = (f32x4)(0.f), e1 = (f32x4)(0.f);
#pragma unroll
  for (int k = 0; k < 5; ++k) {
    const unsigned up = ofu[k];
    float x = fi + asf(up << 16);
    float y = fj + asf(up & 0xFFFF0000u);
    float aw = atf[k];
    float x0f = floorf(x), y0f = floorf(y);
    int ix0 = (int)x0f, iy0 = (int)y0f;
    float wx1 = x - x0f, wy1 = y - y0f;
    float wx0 = 1.f - wx1, wy0 = 1.f - wy1;
    float wya = aw * wy0, wyb = aw * wy1;
    float w00 = wya * wx0, w01 = wya * wx1;
    float w10 = wyb * wx0, w11 = wyb * wx1;
    int ly = iy0 - (J0 - PHALO);
    int lx = ix0 - (I0 - PHALO);
    if ((unsigned)ly <= SPD - 2 && (unsigned)lx <= SPD - 2) {
      const __hip_bfloat16* pb = &patch[ly * SPD + lx][dg * 8];
      acc_cell(pb, w00, a0, a1);
      acc_cell(pb + CELLPAD, w01, e0, e1);
      acc_cell(pb + SPD * CELLPAD, w10, a0, a1);
      acc_cell(pb + SPD * CELLPAD + CELLPAD, w11, e0, e1);
    } else {
      // rare out-of-patch fallback: direct gather with bounds checks
      float wgt[4] = {w00, w01, w10, w11};
#pragma unroll
      for (int cy = 0; cy < 2; ++cy) {
        int iy = iy0 + cy;
        if (iy < 0 || iy >= HWDIM) continue;
#pragma unroll
        for (int cx = 0; cx < 2; ++cx) {
          int ix = ix0 + cx;
          if (ix < 0 || ix >= HWDIM) continue;
          acc_cell(vglob + ((size_t)(iy * HWDIM + ix)) * DHEAD + dg * 8,
                   wgt[cy * 2 + cx], a0, a1);
        }
      }
    }
  }
  f32x4 r0 = a0 + e0;
  f32x4 r1 = a1 + e1;

  // reduce accumulators + exp-sum across the 4 point-groups (lanes ^4, ^8)
#pragma unroll
  for (int m = 4; m <= 8; m <<= 1) {
#pragma unroll
    for (int el = 0; el < 4; ++el) {
      r0[el] += __shfl_xor(r0[el], m);
      r1[el] += __shfl_xor(r1[el], m);
    }
    ssum += __shfl_xor(ssum, m);
  }

  if (pg == 0) {
    const float inv = 1.f / ssum;
    union { short8v v8; __hip_bfloat16 hh[8]; } o;
#pragma unroll
    for (int k = 0; k < 4; ++k) {
      o.hh[k] = __float2bfloat16(r0[k] * inv);
      o.hh[4 + k] = __float2bfloat16(r1[k] * inv);
    }
    *(short8v*)(outat + ((size_t)b * NTOK + n) * CDIM + h * DHEAD + dg * 8) =
        o.v8;
  }
}

extern "C" void kernel_launch(void* const* d_in, const int* in_sizes, int n_in,
                              void* d_out, int out_size, void* d_ws,
                              size_t ws_size, hipStream_t stream) {
  const float* query = (const float*)d_in[0];
  const float* query_pos = (const float*)d_in[1];
  const float* W_val = (const float*)d_in[2];
  const float* b_val = (const float*)d_in[3];
  const float* W_off = (const float*)d_in[4];
  const float* b_off = (const float*)d_in[5];
  const float* W_attn = (const float*)d_in[6];
  const float* b_attn = (const float*)d_in[7];
  const float* W_out1 = (const float*)d_in[8];
  const float* b_out1 = (const float*)d_in[9];
  const float* W_out2 = (const float*)d_in[10];
  const float* b_out2 = (const float*)d_in[11];
  float* out = (float*)d_out;

  char* ws = (char*)d_ws;
  __hip_bfloat16* value = (__hip_bfloat16*)ws;  // (B*NH,N,32) bf16
  ws += (size_t)MROWS * CDIM * 2;
  __hip_bfloat16* offb = (__hip_bfloat16*)ws;   // (B*NH,N,40) bf16
  ws += (size_t)MROWS * 160 * 2;
  float* attnb = (float*)ws;                    // (B*NH,N,20) f32
  ws += (size_t)MROWS * 80 * 4;
  __hip_bfloat16* outat = (__hip_bfloat16*)ws;  // (B,N,C) bf16
  ws += (size_t)MROWS * CDIM * 2;
  float* bcat = (float*)ws; ws += OPAD * 4;
  float* bc = (float*)ws; ws += 128 * 4;
  __hip_bfloat16* Wcat = (__hip_bfloat16*)ws; ws += (size_t)OPAD * 128 * 2;
  __hip_bfloat16* Wc_bf = (__hip_bfloat16*)ws;

  prep_kernel<<<OPAD + 128, 128, 0, stream>>>(
      W_val, b_val, W_off, b_off, W_attn, b_attn, W_out1, b_out1, W_out2,
      b_out2, Wcat, bcat, Wc_bf, bc);

  proj1_kernel<<<dim3(313, 2), 256, 0, stream>>>(query, query_pos, Wcat, bcat,
                                                 value, offb, attnb);

  sample_kernel<<<8 * NPT * NPT, 256, 0, stream>>>(value, offb, attnb, outat);

  proj2_kernel<<<dim3(313, 2), 256, 0, stream>>>(outat, Wc_bf, bc, query, out);
}